// Round 2
// baseline (162.854 us; speedup 1.0000x reference)
//
#include <hip/hip_runtime.h>
#include <hip/hip_cooperative_groups.h>

namespace cg = cooperative_groups;

// B=8, N=256, M=16, D=256
// loss = sum_rows logsumexp_k(S) - sum S_self, S = w*<e,c_k>+b, LOO diagonal
constexpr int B = 8, N = 256, M = 16, D = 256;

typedef short bf16x8 __attribute__((ext_vector_type(8)));
typedef float f32x4 __attribute__((ext_vector_type(4)));

__device__ __forceinline__ unsigned short f2bf(float x) {
  unsigned u = __float_as_uint(x);
  u = (u + 0x7FFFu + ((u >> 16) & 1u)) >> 16;  // RNE
  return (unsigned short)u;
}
__device__ __forceinline__ uint4 packbf8(const float* f) {
  uint4 u;
  u.x = (unsigned)f2bf(f[0]) | ((unsigned)f2bf(f[1]) << 16);
  u.y = (unsigned)f2bf(f[2]) | ((unsigned)f2bf(f[3]) << 16);
  u.z = (unsigned)f2bf(f[4]) | ((unsigned)f2bf(f[5]) << 16);
  u.w = (unsigned)f2bf(f[6]) | ((unsigned)f2bf(f[7]) << 16);
  return u;
}

// ============================================================================
// FUSED single-dispatch cooperative kernel.
// Grid: 512 blocks = (b, strip), 256 threads (4 waves), 2 blocks/CU co-resident.
// Phase 1: wave w owns j = strip*4+w -> centroid (fp32, bit-identical order),
//          A-frags straight into LDS (never touch HBM), row sqnorms into LDS,
//          B-frags (bf16 centroid) to the 1 MB Cbf workspace table.
// grid.sync()  (device-scope fence makes Cbf visible cross-XCD)
// Phase 2: the verified GEMM + LOO/logsumexp epilogue, A from LDS, SQ from LDS.
// Cbf layout (unchanged): uint4[(b*8+kc)*16+nt][lane], lane l = col n=nt*16+(l&15),
//   dims kc*32+(l>>4)*8..+7.
// A_lds layout (= old EbfA per-block slice): uint4[(jt*8+kc)*64+lane], lane l =
//   row m=l&15, dims kc*32+(l>>4)*8..+7.
// ============================================================================
__global__ __launch_bounds__(256, 2) void k_fused(const float* __restrict__ e,
                                                  uint4* __restrict__ Cbf,
                                                  const float* __restrict__ wp,
                                                  const float* __restrict__ bp,
                                                  float* __restrict__ out) {
  const int blk = blockIdx.x;  // b*64 + strip
  const int b = blk >> 6, strip = blk & 63;
  const int tid = threadIdx.x;
  const int wid = tid >> 6, lane = tid & 63;

  __shared__ uint4 A_lds[4 * 8 * 64];  // 32 KB: [jt][kc][lane]
  __shared__ float cbuf[4][D];         // 4 KB: per-wave centroid (already /16)
  __shared__ float sql[64];            // row sqnorms for this block's 64 rows
  __shared__ float lmx[2][64];
  __shared__ float lsm[2][64];
  __shared__ float bred[4];

  // ---- Phase 1 ----
  {
    const int j = strip * 4 + wid;
    const float* base = e + (size_t)(b * 256 + j) * (M * D);

    // centroid: lane owns dims 4*lane..+3; 16 coalesced 1KB wave-loads.
    float4 cv = {0.f, 0.f, 0.f, 0.f};
#pragma unroll
    for (int i = 0; i < M; ++i) {
      float4 v = *(const float4*)(base + i * D + lane * 4);
      cv.x += v.x; cv.y += v.y; cv.z += v.z; cv.w += v.w;
    }
    cv.x *= (1.f / 16.f); cv.y *= (1.f / 16.f);
    cv.z *= (1.f / 16.f); cv.w *= (1.f / 16.f);
    *(float4*)&cbuf[wid][lane * 4] = cv;

    // A-frags + sqnorm: lane -> row m=lane&15, octet q=lane>>4; L1-hot re-read.
    const int m = lane & 15, q = lane >> 4;
    const float* rp = base + m * D + q * 8;
    float sqp = 0.f;
#pragma unroll
    for (int kc = 0; kc < 8; ++kc) {
      float f[8];
      *(float4*)(f) = *(const float4*)(rp + kc * 32);
      *(float4*)(f + 4) = *(const float4*)(rp + kc * 32 + 4);
      A_lds[(wid * 8 + kc) * 64 + lane] = packbf8(f);
#pragma unroll
      for (int x = 0; x < 8; ++x) sqp = fmaf(f[x], f[x], sqp);
    }
    // reduce over q (lane bits 4,5): lanes with same m hold disjoint dim sets.
    sqp += __shfl_xor(sqp, 16, 64);
    sqp += __shfl_xor(sqp, 32, 64);
    if (q == 0) sql[wid * 16 + m] = sqp;
  }
  __syncthreads();  // cbuf/A_lds/sql visible block-wide

  // B-frag write: lanes 0..31 of wave wid pack its centroid j into Cbf.
  if (lane < 32) {
    const int j = strip * 4 + wid;
    float cf[8];
#pragma unroll
    for (int x = 0; x < 8; ++x) cf[x] = cbuf[wid][lane * 8 + x];
    Cbf[((size_t)(b * 8 + (lane >> 2)) * 16 + (j >> 4)) * 64 + (lane & 3) * 16 +
        (j & 15)] = packbf8(cf);
  }
  if (blk == 0 && tid == 0) out[0] = 0.f;  // d_out re-poisoned each launch

  cg::this_grid().sync();

  // ---- Phase 2: GEMM + epilogue (verified structure, A/SQ now LDS-local) ----
  const int h = wid >> 1, c = wid & 1;
  const int q = lane >> 4, cl_ = lane & 15;
  const uint4* Bb = Cbf + (size_t)(b * 128 + c * 8) * 64 + lane;

  f32x4 acc[2][8];
#pragma unroll
  for (int rt = 0; rt < 2; ++rt)
#pragma unroll
    for (int nt = 0; nt < 8; ++nt) acc[rt][nt] = (f32x4)0.f;

#pragma unroll 1
  for (int kc = 0; kc < 8; ++kc) {
    uint4 af0 = A_lds[((h * 2) * 8 + kc) * 64 + lane];
    uint4 af1 = A_lds[((h * 2 + 1) * 8 + kc) * 64 + lane];
    uint4 bfr[8];
#pragma unroll
    for (int nt = 0; nt < 8; ++nt) bfr[nt] = Bb[(kc * 16 + nt) * 64];
    bf16x8 a0 = __builtin_bit_cast(bf16x8, af0);
    bf16x8 a1 = __builtin_bit_cast(bf16x8, af1);
#pragma unroll
    for (int nt = 0; nt < 8; ++nt) {
      bf16x8 bv = __builtin_bit_cast(bf16x8, bfr[nt]);
      acc[0][nt] = __builtin_amdgcn_mfma_f32_16x16x32_bf16(a0, bv, acc[0][nt], 0, 0, 0);
      acc[1][nt] = __builtin_amdgcn_mfma_f32_16x16x32_bf16(a1, bv, acc[1][nt], 0, 0, 0);
    }
  }

  const float w = *wp, bias = *bp;
  float ssum = 0.f;

#pragma unroll
  for (int rt = 0; rt < 2; ++rt) {
    const int jr = strip * 4 + h * 2 + rt;  // global row-tile == diag col
    const bool own = (c == (jr >> 7)) && (cl_ == (jr & 15));
    const int ntd = (jr >> 4) & 7;
    float sq[4];
    if (own) {
#pragma unroll
      for (int reg = 0; reg < 4; ++reg)
        sq[reg] = sql[(h * 2 + rt) * 16 + q * 4 + reg];
    }
#pragma unroll
    for (int nt = 0; nt < 8; ++nt)
#pragma unroll
      for (int reg = 0; reg < 4; ++reg) {
        const float raw = acc[rt][nt][reg];
        float sv = fmaf(w, raw, bias);
        if (own && nt == ntd) {  // predicated select, no indexing
          sv = fmaf(w * (1.f / 15.f), 16.f * raw - sq[reg], bias);
          ssum += sv;
        }
        acc[rt][nt][reg] = sv;
      }
#pragma unroll
    for (int reg = 0; reg < 4; ++reg) {
      float mx = acc[rt][0][reg];
#pragma unroll
      for (int nt = 1; nt < 8; ++nt) mx = fmaxf(mx, acc[rt][nt][reg]);
#pragma unroll
      for (int mk = 1; mk < 16; mk <<= 1) mx = fmaxf(mx, __shfl_xor(mx, mk, 64));
      if (cl_ == 0) lmx[c][(h * 2 + rt) * 16 + q * 4 + reg] = mx;
    }
  }
  __syncthreads();

#pragma unroll
  for (int rt = 0; rt < 2; ++rt)
#pragma unroll
    for (int reg = 0; reg < 4; ++reg) {
      const int Rl = (h * 2 + rt) * 16 + q * 4 + reg;
      const float mx = fmaxf(lmx[0][Rl], lmx[1][Rl]);
      float se = 0.f;
#pragma unroll
      for (int nt = 0; nt < 8; ++nt) se += __expf(acc[rt][nt][reg] - mx);
#pragma unroll
      for (int mk = 1; mk < 16; mk <<= 1) se += __shfl_xor(se, mk, 64);
      if (cl_ == 0) lsm[c][Rl] = se;
    }
  __syncthreads();

  float part = -ssum;
  if (c == 0 && cl_ == 0) {
#pragma unroll
    for (int rt = 0; rt < 2; ++rt)
#pragma unroll
      for (int reg = 0; reg < 4; ++reg) {
        const int Rl = (h * 2 + rt) * 16 + q * 4 + reg;
        const float mx = fmaxf(lmx[0][Rl], lmx[1][Rl]);
        part += mx + __logf(lsm[0][Rl] + lsm[1][Rl]);
      }
  }
#pragma unroll
  for (int mk = 1; mk < 64; mk <<= 1) part += __shfl_xor(part, mk, 64);
  if (lane == 0) bred[wid] = part;
  __syncthreads();
  if (tid == 0) atomicAdd(out, bred[0] + bred[1] + bred[2] + bred[3]);
}

// ============================================================================
// FALLBACK path (bit-identical to the round-1 verified two-kernel version).
// Used only if the cooperative launch is rejected (e.g. under graph capture).
// ============================================================================
__global__ __launch_bounds__(256) void k_prep(const float* __restrict__ e,
                                              uint4* __restrict__ EbfA,
                                              uint4* __restrict__ Cbf,
                                              float* __restrict__ SQ,
                                              float* __restrict__ out) {
  const int blk = blockIdx.x;  // b*256 + j
  const int b = blk >> 8, j = blk & 255;
  const int t = threadIdx.x;
  const float* base = e + (size_t)blk * (M * D);

  __shared__ float cbuf[D];
  __shared__ float sqred[4][16];

  float cs = 0.f;
#pragma unroll
  for (int i = 0; i < M; ++i) cs += base[i * D + t];
  cbuf[t] = cs * (1.f / 16.f);

  const int m = t & 15, o2 = t >> 4;
  const float* p0 = base + m * D + o2 * 8;
  float f0[8], f1[8];
  *(float4*)(f0) = *(const float4*)(p0);
  *(float4*)(f0 + 4) = *(const float4*)(p0 + 4);
  *(float4*)(f1) = *(const float4*)(p0 + 128);
  *(float4*)(f1 + 4) = *(const float4*)(p0 + 132);

  EbfA[(size_t)(blk * 8 + (o2 >> 2)) * 64 + (o2 & 3) * 16 + m] = packbf8(f0);
  EbfA[(size_t)(blk * 8 + 4 + (o2 >> 2)) * 64 + (o2 & 3) * 16 + m] = packbf8(f1);

  float sqp = 0.f;
#pragma unroll
  for (int x = 0; x < 8; ++x) sqp = fmaf(f0[x], f0[x], fmaf(f1[x], f1[x], sqp));
  sqp += __shfl_xor(sqp, 16, 64);
  sqp += __shfl_xor(sqp, 32, 64);
  const int w = t >> 6;
  if ((t & 63) < 16) sqred[w][m] = sqp;
  __syncthreads();

  if (t < 32) {
    float cf[8];
#pragma unroll
    for (int x = 0; x < 8; ++x) cf[x] = cbuf[t * 8 + x];
    Cbf[((size_t)(b * 8 + (t >> 2)) * 16 + (j >> 4)) * 64 + (t & 3) * 16 + (j & 15)] =
        packbf8(cf);
  }
  if (t < 16) SQ[blk * 16 + t] = sqred[0][t] + sqred[1][t] + sqred[2][t] + sqred[3][t];
  if (blk == 0 && t == 0) out[0] = 0.f;
}

__global__ __launch_bounds__(256) void k_gemm(const uint4* __restrict__ EbfA,
                                              const uint4* __restrict__ Cbf,
                                              const float* __restrict__ SQ,
                                              const float* __restrict__ wp,
                                              const float* __restrict__ bp,
                                              float* __restrict__ out) {
  const int blk = blockIdx.x;  // b*64 + strip
  const int b = blk >> 6, strip = blk & 63;
  const int tid = threadIdx.x;
  const int wid = tid >> 6, lane = tid & 63;
  const int h = wid >> 1, c = wid & 1;
  const int q = lane >> 4, cl_ = lane & 15;

  const uint4* Ab = EbfA + (size_t)((b * 256 + strip * 4 + h * 2) * 8) * 64 + lane;
  const uint4* Bb = Cbf + (size_t)(b * 128 + c * 8) * 64 + lane;

  f32x4 acc[2][8];
#pragma unroll
  for (int rt = 0; rt < 2; ++rt)
#pragma unroll
    for (int nt = 0; nt < 8; ++nt) acc[rt][nt] = (f32x4)0.f;

#pragma unroll 1
  for (int kc = 0; kc < 8; ++kc) {
    uint4 af0 = Ab[kc * 64];
    uint4 af1 = Ab[(8 + kc) * 64];
    uint4 bfr[8];
#pragma unroll
    for (int nt = 0; nt < 8; ++nt) bfr[nt] = Bb[(kc * 16 + nt) * 64];
    bf16x8 a0 = __builtin_bit_cast(bf16x8, af0);
    bf16x8 a1 = __builtin_bit_cast(bf16x8, af1);
#pragma unroll
    for (int nt = 0; nt < 8; ++nt) {
      bf16x8 bv = __builtin_bit_cast(bf16x8, bfr[nt]);
      acc[0][nt] = __builtin_amdgcn_mfma_f32_16x16x32_bf16(a0, bv, acc[0][nt], 0, 0, 0);
      acc[1][nt] = __builtin_amdgcn_mfma_f32_16x16x32_bf16(a1, bv, acc[1][nt], 0, 0, 0);
    }
  }

  const float w = *wp, bias = *bp;
  __shared__ float lmx[2][64];
  __shared__ float lsm[2][64];
  __shared__ float bred[4];
  float ssum = 0.f;

#pragma unroll
  for (int rt = 0; rt < 2; ++rt) {
    const int jr = strip * 4 + h * 2 + rt;
    const bool own = (c == (jr >> 7)) && (cl_ == (jr & 15));
    const int ntd = (jr >> 4) & 7;
    float sq[4];
    if (own) {
#pragma unroll
      for (int reg = 0; reg < 4; ++reg)
        sq[reg] = SQ[b * 4096 + strip * 64 + (h * 2 + rt) * 16 + q * 4 + reg];
    }
#pragma unroll
    for (int nt = 0; nt < 8; ++nt)
#pragma unroll
      for (int reg = 0; reg < 4; ++reg) {
        const float raw = acc[rt][nt][reg];
        float sv = fmaf(w, raw, bias);
        if (own && nt == ntd) {
          sv = fmaf(w * (1.f / 15.f), 16.f * raw - sq[reg], bias);
          ssum += sv;
        }
        acc[rt][nt][reg] = sv;
      }
#pragma unroll
    for (int reg = 0; reg < 4; ++reg) {
      float mx = acc[rt][0][reg];
#pragma unroll
      for (int nt = 1; nt < 8; ++nt) mx = fmaxf(mx, acc[rt][nt][reg]);
#pragma unroll
      for (int mk = 1; mk < 16; mk <<= 1) mx = fmaxf(mx, __shfl_xor(mx, mk, 64));
      if (cl_ == 0) lmx[c][(h * 2 + rt) * 16 + q * 4 + reg] = mx;
    }
  }
  __syncthreads();

#pragma unroll
  for (int rt = 0; rt < 2; ++rt)
#pragma unroll
    for (int reg = 0; reg < 4; ++reg) {
      const int Rl = (h * 2 + rt) * 16 + q * 4 + reg;
      const float mx = fmaxf(lmx[0][Rl], lmx[1][Rl]);
      float se = 0.f;
#pragma unroll
      for (int nt = 0; nt < 8; ++nt) se += __expf(acc[rt][nt][reg] - mx);
#pragma unroll
      for (int mk = 1; mk < 16; mk <<= 1) se += __shfl_xor(se, mk, 64);
      if (cl_ == 0) lsm[c][Rl] = se;
    }
  __syncthreads();

  float part = -ssum;
  if (c == 0 && cl_ == 0) {
#pragma unroll
    for (int rt = 0; rt < 2; ++rt)
#pragma unroll
      for (int reg = 0; reg < 4; ++reg) {
        const int Rl = (h * 2 + rt) * 16 + q * 4 + reg;
        const float mx = fmaxf(lmx[0][Rl], lmx[1][Rl]);
        part += mx + __logf(lsm[0][Rl] + lsm[1][Rl]);
      }
  }
#pragma unroll
  for (int mk = 1; mk < 64; mk <<= 1) part += __shfl_xor(part, mk, 64);
  if (lane == 0) bred[wid] = part;
  __syncthreads();
  if (tid == 0) atomicAdd(out, bred[0] + bred[1] + bred[2] + bred[3]);
}

extern "C" void kernel_launch(void* const* d_in, const int* in_sizes, int n_in,
                              void* d_out, int out_size, void* d_ws, size_t ws_size,
                              hipStream_t stream) {
  const float* e = (const float*)d_in[0];
  const float* wp = (const float*)d_in[1];
  const float* bp = (const float*)d_in[2];
  float* out = (float*)d_out;
  char* ws = (char*)d_ws;
  uint4* EbfA = (uint4*)ws;                              // 16 MB (fallback only)
  uint4* Cbf = (uint4*)(ws + (size_t)16 * 1024 * 1024);  // 1 MB
  float* SQ = (float*)(ws + (size_t)17 * 1024 * 1024);   // 128 KB (fallback only)

  void* args[] = {(void*)&e, (void*)&Cbf, (void*)&wp, (void*)&bp, (void*)&out};
  hipError_t err = hipLaunchCooperativeKernel((const void*)k_fused, dim3(B * 64),
                                              dim3(256), args, 0, stream);
  if (err != hipSuccess) {
    // cooperative launch unavailable (e.g. under capture) -> verified 2-kernel path
    k_prep<<<B * N, 256, 0, stream>>>(e, EbfA, Cbf, SQ, out);
    k_gemm<<<B * 64, 256, 0, stream>>>(EbfA, Cbf, SQ, wp, bp, out);
  }
}

// Round 3
// 99.577 us; speedup vs baseline: 1.6355x; 1.6355x over previous
//
#include <hip/hip_runtime.h>

// B=8, N=256, M=16, D=256
// loss = sum_rows logsumexp_k(S) - sum S_self, S = w*<e,c_k>+b, LOO diagonal
constexpr int B = 8, N = 256, M = 16, D = 256;

typedef short bf16x8 __attribute__((ext_vector_type(8)));
typedef float f32x4 __attribute__((ext_vector_type(4)));

__device__ __forceinline__ unsigned short f2bf(float x) {
  unsigned u = __float_as_uint(x);
  u = (u + 0x7FFFu + ((u >> 16) & 1u)) >> 16;  // RNE
  return (unsigned short)u;
}
__device__ __forceinline__ uint4 packbf8(const float* f) {
  uint4 u;
  u.x = (unsigned)f2bf(f[0]) | ((unsigned)f2bf(f[1]) << 16);
  u.y = (unsigned)f2bf(f[2]) | ((unsigned)f2bf(f[3]) << 16);
  u.z = (unsigned)f2bf(f[4]) | ((unsigned)f2bf(f[5]) << 16);
  u.w = (unsigned)f2bf(f[6]) | ((unsigned)f2bf(f[7]) << 16);
  return u;
}

// ws: Cbf [0,1MB) B-frags: uint4[(b*8+kc)*16+nt][lane], lane l = col n=nt*16+(l&15),
//     dims kc*32+(l>>4)*8..+7.   (EbfA/SQ eliminated: A-frags + sqnorms never touch HBM.)

// k_cent: one block per (b,j). Centroid only — thread t owns dim d=t, serial sum
// over M=16 rows (16 fully-coalesced 1KB wave-loads, zero cross-lane traffic),
// then threads 0..31 pack the bf16 B-fragment. Verified numeric path (rounds 1-2).
__global__ __launch_bounds__(256) void k_cent(const float* __restrict__ e,
                                              uint4* __restrict__ Cbf,
                                              float* __restrict__ out) {
  const int blk = blockIdx.x;  // b*256 + j
  const int b = blk >> 8, j = blk & 255;
  const int t = threadIdx.x;
  const float* base = e + (size_t)blk * (M * D);

  __shared__ float cbuf[D];
  float cs = 0.f;
#pragma unroll
  for (int i = 0; i < M; ++i) cs += base[i * D + t];
  cbuf[t] = cs * (1.f / 16.f);
  __syncthreads();

  if (t < 32) {
    float cf[8];
#pragma unroll
    for (int x = 0; x < 8; ++x) cf[x] = cbuf[t * 8 + x];
    Cbf[((size_t)(b * 8 + (t >> 2)) * 16 + (j >> 4)) * 64 + (t & 3) * 16 + (j & 15)] =
        packbf8(cf);
  }
  if (blk == 0 && t == 0) out[0] = 0.f;  // d_out re-poisoned each launch
}

// k_gemm2: one block per (b, 64-row strip) [512 blocks, 4 waves].
// Phase 1 (from verified k_fused): wave wid packs A-frags of j=strip*4+wid from e
//   straight into LDS (32 KB, never HBM) and computes row sqnorms into sql.
// Phase 2: verified GEMM + LOO/logsumexp epilogue; B-frags from the 1 MB Cbf table.
// A_lds layout: uint4[(jt*8+kc)*64+lane], lane l = row m=l&15, dims kc*32+(l>>4)*8..+7.
__global__ __launch_bounds__(256) void k_gemm2(const float* __restrict__ e,
                                               const uint4* __restrict__ Cbf,
                                               const float* __restrict__ wp,
                                               const float* __restrict__ bp,
                                               float* __restrict__ out) {
  const int blk = blockIdx.x;  // b*64 + strip
  const int b = blk >> 6, strip = blk & 63;
  const int tid = threadIdx.x;
  const int wid = tid >> 6, lane = tid & 63;

  __shared__ uint4 A_lds[4 * 8 * 64];  // 32 KB: [jt][kc][lane]
  __shared__ float sql[64];            // row sqnorms for this block's 64 rows
  __shared__ float lmx[2][64];
  __shared__ float lsm[2][64];
  __shared__ float bred[4];

  // ---- Phase 1: A-frag pack + sqnorm (verified k_fused code) ----
  {
    const int j = strip * 4 + wid;
    const float* base = e + (size_t)(b * 256 + j) * (M * D);
    const int m = lane & 15, q = lane >> 4;
    const float* rp = base + m * D + q * 8;
    float sqp = 0.f;
#pragma unroll
    for (int kc = 0; kc < 8; ++kc) {
      float f[8];
      *(float4*)(f) = *(const float4*)(rp + kc * 32);
      *(float4*)(f + 4) = *(const float4*)(rp + kc * 32 + 4);
      A_lds[(wid * 8 + kc) * 64 + lane] = packbf8(f);
#pragma unroll
      for (int x = 0; x < 8; ++x) sqp = fmaf(f[x], f[x], sqp);
    }
    // reduce over q (lane bits 4,5): lanes with same m hold disjoint dim sets.
    sqp += __shfl_xor(sqp, 16, 64);
    sqp += __shfl_xor(sqp, 32, 64);
    if (q == 0) sql[wid * 16 + m] = sqp;
  }
  __syncthreads();  // A_lds/sql visible block-wide

  // ---- Phase 2: GEMM + epilogue (verified structure) ----
  const int h = wid >> 1, c = wid & 1;
  const int q = lane >> 4, cl_ = lane & 15;
  const uint4* Bb = Cbf + (size_t)(b * 128 + c * 8) * 64 + lane;

  f32x4 acc[2][8];
#pragma unroll
  for (int rt = 0; rt < 2; ++rt)
#pragma unroll
    for (int nt = 0; nt < 8; ++nt) acc[rt][nt] = (f32x4)0.f;

#pragma unroll 1
  for (int kc = 0; kc < 8; ++kc) {
    uint4 af0 = A_lds[((h * 2) * 8 + kc) * 64 + lane];
    uint4 af1 = A_lds[((h * 2 + 1) * 8 + kc) * 64 + lane];
    uint4 bfr[8];
#pragma unroll
    for (int nt = 0; nt < 8; ++nt) bfr[nt] = Bb[(kc * 16 + nt) * 64];
    bf16x8 a0 = __builtin_bit_cast(bf16x8, af0);
    bf16x8 a1 = __builtin_bit_cast(bf16x8, af1);
#pragma unroll
    for (int nt = 0; nt < 8; ++nt) {
      bf16x8 bv = __builtin_bit_cast(bf16x8, bfr[nt]);
      acc[0][nt] = __builtin_amdgcn_mfma_f32_16x16x32_bf16(a0, bv, acc[0][nt], 0, 0, 0);
      acc[1][nt] = __builtin_amdgcn_mfma_f32_16x16x32_bf16(a1, bv, acc[1][nt], 0, 0, 0);
    }
  }

  const float w = *wp, bias = *bp;
  float ssum = 0.f;

#pragma unroll
  for (int rt = 0; rt < 2; ++rt) {
    const int jr = strip * 4 + h * 2 + rt;  // global row-tile == diag col
    const bool own = (c == (jr >> 7)) && (cl_ == (jr & 15));
    const int ntd = (jr >> 4) & 7;
    float sq[4];
    if (own) {
#pragma unroll
      for (int reg = 0; reg < 4; ++reg)
        sq[reg] = sql[(h * 2 + rt) * 16 + q * 4 + reg];
    }
#pragma unroll
    for (int nt = 0; nt < 8; ++nt)
#pragma unroll
      for (int reg = 0; reg < 4; ++reg) {
        const float raw = acc[rt][nt][reg];
        float sv = fmaf(w, raw, bias);
        if (own && nt == ntd) {  // predicated select, no indexing
          sv = fmaf(w * (1.f / 15.f), 16.f * raw - sq[reg], bias);
          ssum += sv;
        }
        acc[rt][nt][reg] = sv;
      }
#pragma unroll
    for (int reg = 0; reg < 4; ++reg) {
      float mx = acc[rt][0][reg];
#pragma unroll
      for (int nt = 1; nt < 8; ++nt) mx = fmaxf(mx, acc[rt][nt][reg]);
#pragma unroll
      for (int mk = 1; mk < 16; mk <<= 1) mx = fmaxf(mx, __shfl_xor(mx, mk, 64));
      if (cl_ == 0) lmx[c][(h * 2 + rt) * 16 + q * 4 + reg] = mx;
    }
  }
  __syncthreads();

#pragma unroll
  for (int rt = 0; rt < 2; ++rt)
#pragma unroll
    for (int reg = 0; reg < 4; ++reg) {
      const int Rl = (h * 2 + rt) * 16 + q * 4 + reg;
      const float mx = fmaxf(lmx[0][Rl], lmx[1][Rl]);
      float se = 0.f;
#pragma unroll
      for (int nt = 0; nt < 8; ++nt) se += __expf(acc[rt][nt][reg] - mx);
#pragma unroll
      for (int mk = 1; mk < 16; mk <<= 1) se += __shfl_xor(se, mk, 64);
      if (cl_ == 0) lsm[c][Rl] = se;
    }
  __syncthreads();

  float part = -ssum;
  if (c == 0 && cl_ == 0) {
#pragma unroll
    for (int rt = 0; rt < 2; ++rt)
#pragma unroll
      for (int reg = 0; reg < 4; ++reg) {
        const int Rl = (h * 2 + rt) * 16 + q * 4 + reg;
        const float mx = fmaxf(lmx[0][Rl], lmx[1][Rl]);
        part += mx + __logf(lsm[0][Rl] + lsm[1][Rl]);
      }
  }
#pragma unroll
  for (int mk = 1; mk < 64; mk <<= 1) part += __shfl_xor(part, mk, 64);
  if (lane == 0) bred[wid] = part;
  __syncthreads();
  if (tid == 0) atomicAdd(out, bred[0] + bred[1] + bred[2] + bred[3]);
}

extern "C" void kernel_launch(void* const* d_in, const int* in_sizes, int n_in,
                              void* d_out, int out_size, void* d_ws, size_t ws_size,
                              hipStream_t stream) {
  const float* e = (const float*)d_in[0];
  const float* wp = (const float*)d_in[1];
  const float* bp = (const float*)d_in[2];
  float* out = (float*)d_out;
  uint4* Cbf = (uint4*)d_ws;  // 1 MB

  k_cent<<<B * N, 256, 0, stream>>>(e, Cbf, out);
  k_gemm2<<<B * 64, 256, 0, stream>>>(e, Cbf, wp, bp, out);
}